// Round 17
// baseline (218.408 us; speedup 1.0000x reference)
//
#include <hip/hip_runtime.h>

// Problem constants (fixed by setup_inputs)
constexpr int Bb = 4;
constexpr int Nn = 20000;
constexpr int Ff = 64;
constexpr int Hh = 128;
constexpr float BN_EPS = 1e-5f;
constexpr int NSLOTS = 64;               // BN-stat atomic spread (k_stat only)
constexpr int NB = (Nn + 1023) / 1024;   // scan blocks (20)

typedef __attribute__((ext_vector_type(8))) short bf16x8;
typedef __attribute__((ext_vector_type(4))) float f32x4;

// bf16 helpers (RNE pack, cheap unpack)
__device__ inline unsigned f2bf(float f) {
    unsigned u = __float_as_uint(f);
    return (u + 0x7fffu + ((u >> 16) & 1u)) >> 16;
}
__device__ inline unsigned pack2(float lo, float hi) { return f2bf(lo) | (f2bf(hi) << 16); }
__device__ inline float bf_lo(unsigned w) { return __uint_as_float(w << 16); }
__device__ inline float bf_hi(unsigned w) { return __uint_as_float(w & 0xffff0000u); }

template <int NU>
__device__ inline void ldrow(unsigned* u, const unsigned* p) {
    if constexpr (NU == 2) { const uint2 t = *(const uint2*)p; u[0] = t.x; u[1] = t.y; }
    else { const uint4 t = *(const uint4*)p; u[0] = t.x; u[1] = t.y; u[2] = t.z; u[3] = t.w; }
}
template <int NU>
__device__ inline void acc_row(float* a, const unsigned* u, float nm) {
#pragma unroll
    for (int c = 0; c < NU; ++c) {
        a[2 * c]     = fmaf(nm, bf_lo(u[c]), a[2 * c]);
        a[2 * c + 1] = fmaf(nm, bf_hi(u[c]), a[2 * c + 1]);
    }
}

// ---------------------------------------------------------------------------
// K1: merged pre-pass: [0,NDEG) deg-count | [NDEG,NDEG+NCVT) x->bf16 cvt
// (OUTPUT-linear: contiguous xb writes; reads are 4 streams of 256B segments)
// | [NDEG+NCVT, +32) W1 frag-linear transpose. All independent.
__global__ __launch_bounds__(256) void k_pre(const int* __restrict__ dst, int E,
                                             int NDEG,
                                             int* __restrict__ deg,
                                             const float* __restrict__ x,
                                             unsigned* __restrict__ xb,
                                             const float* __restrict__ W1,
                                             unsigned short* __restrict__ WTf) {
    const int b = blockIdx.x;
    if (b < NDEG) {
        const int e = b * 256 + threadIdx.x;
        if (e < E) atomicAdd(&deg[dst[e]], 1);
    } else if (b < NDEG + (Bb * Nn * 32) / 256) {
        const int o = (b - NDEG) * 256 + threadIdx.x;   // OUTPUT uint index
        const int n   = o >> 7;           // node
        const int rem = o & 127;
        const int bb  = rem >> 5;         // batch
        const int c2  = rem & 31;         // channel pair
        const float2 v = *(const float2*)&x[(((size_t)bb * Nn + n) * 64) + c2 * 2];
        xb[o] = pack2(v.x, v.y);
    } else {
        const int f = (b - NDEG - (Bb * Nn * 32) / 256) * 256 + threadIdx.x;
        if (f < 128 * Ff) {
            const int j = f & 7, lane = (f >> 3) & 63, rest = f >> 9;
            const int ks = rest & 1, tt = rest >> 1;
            const int col = tt * 16 + (lane & 15);
            const int k = ks * 32 + ((lane >> 4) << 3) + j;
            WTf[f] = (unsigned short)f2bf(W1[(size_t)k * 128 + col]);
        }
    }
}

// ---------------------------------------------------------------------------
// K2: ONE-launch scan (R15-verified correct; R15's regression isolated to the
// threadfence stat-finalize, not this). Each of NB blocks redundantly sums its
// prefix of (deg+1), then scans its own tile locally. No inter-block handoff.
__global__ __launch_bounds__(1024) void k_scanall(const int* __restrict__ deg,
                                                  int* __restrict__ rowptr,
                                                  int* __restrict__ cursor,
                                                  float* __restrict__ dinv) {
    __shared__ int red[16];
    __shared__ int woff[16];
    __shared__ int base_s;
    const int tid = threadIdx.x, lane = tid & 63, wid = tid >> 6;
    const int b = blockIdx.x;

    // (1) base = sum of (deg+1) over [0, b*1024)
    int pre = 0;
    for (int i = tid; i < b * 1024; i += 1024) pre += deg[i] + 1;
#pragma unroll
    for (int d = 32; d; d >>= 1) pre += __shfl_down(pre, d);
    if (lane == 0) red[wid] = pre;
    __syncthreads();                      // B1
    if (tid == 0) {
        int s = 0;
        for (int w = 0; w < 16; ++w) s += red[w];
        base_s = s;
    }

    // (2) local inclusive scan of this tile
    const int i = b * 1024 + tid;
    const int cnt = (i < Nn) ? deg[i] + 1 : 0;
    int v = cnt;
#pragma unroll
    for (int d = 1; d < 64; d <<= 1) {
        const int t = __shfl_up(v, d);
        if (lane >= d) v += t;
    }
    __syncthreads();                      // B2
    if (lane == 63) red[wid] = v;
    __syncthreads();                      // B3
    if (wid == 0) {
        const int orig = (lane < 16) ? red[lane] : 0;
        int w = orig;
#pragma unroll
        for (int d = 1; d < 16; d <<= 1) {
            const int t = __shfl_up(w, d);
            if (lane >= d) w += t;
        }
        if (lane < 16) woff[lane] = w - orig;
    }
    __syncthreads();                      // B4
    if (i < Nn) {
        const int excl = base_s + woff[wid] + (v - cnt);
        rowptr[i] = excl;
        cursor[i] = excl;
        dinv[i] = rsqrtf((float)cnt);
        if (i == Nn - 1) rowptr[Nn] = excl + cnt;
    }
}

// ---------------------------------------------------------------------------
// K3: fill CSR + per-edge norm + per-node nsum (= sum of norms, for BN-fold)
__global__ void k_fill(const int* __restrict__ src, const int* __restrict__ dst, int E,
                       const float* __restrict__ dinv, int* __restrict__ cursor,
                       int* __restrict__ csr_src, float* __restrict__ csr_norm,
                       float* __restrict__ nsum) {
    int t = blockIdx.x * blockDim.x + threadIdx.x;
    int s, d;
    if (t < E) { s = src[t]; d = dst[t]; }
    else if (t < E + Nn) { s = d = t - E; }
    else return;
    int pos = atomicAdd(&cursor[d], 1);
    const float nm = dinv[s] * dinv[d];
    csr_src[pos]  = s;
    csr_norm[pos] = nm;
    atomicAdd(&nsum[d], nm);
}

// ---------------------------------------------------------------------------
// K4: BN stats pass over h [80000][128] bf16 (read as uint[...][64]).
// Grid-stride; col = 2*(tid&63) fixed per thread; LDS-reduce; spread slots.
__global__ __launch_bounds__(256) void k_stat(const unsigned* __restrict__ h,
                                              float* __restrict__ gsum,
                                              float* __restrict__ gsq) {
    __shared__ float lsum[128], lsq[128];
    const int tid = threadIdx.x;
    if (tid < 128) { lsum[tid] = 0.f; lsq[tid] = 0.f; }
    __syncthreads();
    constexpr int TOTAL = Bb * Nn * (Hh / 2);        // 5.12M uints
    const int stride = gridDim.x * 256;              // multiple of 64
    float s0 = 0.f, s1 = 0.f, q0 = 0.f, q1 = 0.f;
    for (int i = blockIdx.x * 256 + tid; i < TOTAL; i += stride) {
        const unsigned w = h[i];
        const float lo = bf_lo(w), hi = bf_hi(w);
        s0 += lo; s1 += hi;
        q0 = fmaf(lo, lo, q0); q1 = fmaf(hi, hi, q1);
    }
    const int c0 = (tid & 63) * 2;
    atomicAdd(&lsum[c0], s0);     atomicAdd(&lsum[c0 + 1], s1);
    atomicAdd(&lsq[c0],  q0);     atomicAdd(&lsq[c0 + 1],  q1);
    __syncthreads();
    float* gs = gsum + (size_t)(blockIdx.x & (NSLOTS - 1)) * 128;
    float* gq = gsq  + (size_t)(blockIdx.x & (NSLOTS - 1)) * 128;
    if (tid < 128) { atomicAdd(&gs[tid], lsum[tid]); atomicAdd(&gq[tid], lsq[tid]); }
}

// ---------------------------------------------------------------------------
// K5: fused BN1-finalize + WT2 fold (frag-linear) + shW2. Every block
// redundantly reduces 64-slot stats; blocks 0..63 write WT2f, block 64 shW2.
__global__ __launch_bounds__(128) void k_prep2(const float* __restrict__ gsum,
                                               const float* __restrict__ gsq,
                                               const float* __restrict__ gamma,
                                               const float* __restrict__ beta,
                                               const float* __restrict__ W2,
                                               unsigned short* __restrict__ WT2f,
                                               float* __restrict__ shW2) {
    __shared__ float sc_s[128], sh_s[128];
    const int c = threadIdx.x;
    float s = 0.f, q = 0.f;
    for (int j = 0; j < NSLOTS; ++j) { s += gsum[j * 128 + c]; q += gsq[j * 128 + c]; }
    const float inv = 1.0f / (float)(Bb * Nn);
    const float mu  = s * inv;
    const float var = q * inv - mu * mu;
    const float sc  = gamma[c] * rsqrtf(var + BN_EPS);
    sc_s[c] = sc;
    sh_s[c] = beta[c] - mu * sc;
    __syncthreads();
    if (blockIdx.x < 64) {
#pragma unroll
        for (int i = 0; i < 2; ++i) {
            const int f = blockIdx.x * 256 + i * 128 + c;
            const int j = f & 7, lane = (f >> 3) & 63, rest = f >> 9;  // 0..31
            const int ks = rest & 3, tt = rest >> 2;
            const int col = tt * 16 + (lane & 15);
            const int k = ks * 32 + ((lane >> 4) << 3) + j;
            WT2f[f] = (unsigned short)f2bf(sc_s[k] * W2[(size_t)k * 128 + col]);
        }
    } else {
        float a = 0.f;
        for (int k = 0; k < 128; ++k) a = fmaf(sh_s[k], W2[(size_t)k * 128 + c], a);
        shW2[c] = a;
    }
}

// ---------------------------------------------------------------------------
// K6: FUSED gather-aggregate + MFMA GEMM. 128-thread block = TWO independent
// waves (disjoint sA/sO, zero barriers) — tests the workgroup-slot-cap theory:
// 10000 1-wave blocks stuck at ~20 waves/CU (62%); 2-wave blocks double
// waves-per-slot. Per-wave structure identical to R16 (2 nodes, UNR diet,
// sO LDS-transit stores).
template <int K, bool L2E>
__global__ __launch_bounds__(128, 8) void k_fmm(const unsigned* __restrict__ G,
                                                const int* __restrict__ rowptr,
                                                const int* __restrict__ csr_src,
                                                const float* __restrict__ csr_norm,
                                                const unsigned short* __restrict__ WTf,
                                                const float* __restrict__ bias,
                                                const float* __restrict__ nsum,
                                                const float* __restrict__ shW2,
                                                unsigned short* __restrict__ Yout) {
    constexpr int NKS = K / 32;
    constexpr int AST = K + 8;
    constexpr int NU = K / 32;        // uints per lane per edge (2 or 4)
    constexpr int UNR = (K == 128) ? 4 : 8;   // in-flight gathers (VGPR diet)
    constexpr int ROWU = Bb * K / 2;  // uints per node row (128 or 256)
    constexpr int WSLOT = 16 * AST + (K == 64 ? 1024 : 0);  // 2176 both
    __shared__ alignas(16) unsigned short sAall[2 * WSLOT];

    const int w = threadIdx.x >> 6;   // wave id in block
    const int lane = threadIdx.x & 63;
    unsigned short* const sA = &sAall[w * WSLOT];
    unsigned short* const sO = (K == 64) ? &sA[16 * AST] : &sA[8 * AST];

    const int cg = lane & 15, kg = lane >> 4;
    const int g = blockIdx.x * 2 + w; // node pair: nodes 2g, 2g+1
    const int row0 = g * 8;

    // gather 2 nodes into sA rows 0..7 (no barriers anywhere)
#pragma unroll
    for (int j = 0; j < 2; ++j) {
        const int v = g * 2 + j;
        const int beg = rowptr[v], end = rowptr[v + 1];
        float a[2 * NU];
#pragma unroll
        for (int c = 0; c < 2 * NU; ++c) a[c] = 0.f;
        int e = beg;
        for (; e + UNR <= end; e += UNR) {
            unsigned u[UNR][NU];
            int si[UNR];
#pragma unroll
            for (int q = 0; q < UNR; ++q) si[q] = csr_src[e + q];
#pragma unroll
            for (int q = 0; q < UNR; ++q)
                ldrow<NU>(u[q], G + (size_t)si[q] * ROWU + lane * NU);
#pragma unroll
            for (int q = 0; q < UNR; ++q) acc_row<NU>(a, u[q], csr_norm[e + q]);
        }
        for (; e < end; ++e) {
            unsigned u[NU];
            ldrow<NU>(u, G + (size_t)csr_src[e] * ROWU + lane * NU);
            acc_row<NU>(a, u, csr_norm[e]);
        }
        const int row = j * 4 + kg;       // node-major row = node*4 + batch
        unsigned p[NU];
#pragma unroll
        for (int c = 0; c < NU; ++c) p[c] = pack2(a[2 * c], a[2 * c + 1]);
        if constexpr (NU == 2) *(uint2*)&sA[row * AST + cg * 4] = *(const uint2*)p;
        else                   *(uint4*)&sA[row * AST + cg * 8] = *(const uint4*)p;
    }
    // same-wave LDS RAW: compiler lgkmcnt handles ordering; no barrier.

    // MFMA: A rows = cg (0..15; 8..15 stale -> rows never emitted), B from WTf
    f32x4 acc[8];
#pragma unroll
    for (int t = 0; t < 8; ++t) acc[t] = (f32x4){0.f, 0.f, 0.f, 0.f};
#pragma unroll
    for (int ks = 0; ks < NKS; ++ks) {
        const bf16x8 av = *(const bf16x8*)&sA[cg * AST + ks * 32 + kg * 8];
#pragma unroll
        for (int t = 0; t < 8; ++t) {
            const bf16x8 bv = *(const bf16x8*)&WTf[(size_t)((t * NKS + ks) * 64 + lane) * 8];
            acc[t] = __builtin_amdgcn_mfma_f32_16x16x32_bf16(av, bv, acc[t], 0, 0, 0);
        }
    }

    // epilogue: valid rows (kg<2) -> bf16 into sO (aliases sA rows 8..15 for
    // K=128, written only after last ds_read; DS pipe in-order per wave);
    // then all 64 lanes store 2KB as two contiguous 1KB instructions.
    if (kg < 2) {
        const int rbase = kg * 4;         // node g*2+kg, 4 batches
        float ns = 0.f;
        if (L2E) ns = nsum[g * 2 + kg];
#pragma unroll
        for (int t = 0; t < 8; ++t) {
            const int col = t * 16 + cg;
            float badd = bias[col];
            if (L2E) badd = fmaf(ns, shW2[col], badd);
#pragma unroll
            for (int jj = 0; jj < 4; ++jj) {
                const float y = fmaxf(acc[t][jj] + badd, 0.f);
                sO[(rbase + jj) * 128 + col] = (unsigned short)f2bf(y);
            }
        }
    }
    const size_t obase = (size_t)row0 * 128;
#pragma unroll
    for (int h = 0; h < 2; ++h) {
        const int i16 = h * 64 + lane;    // uint4 index: contiguous 1KB/instr
        *(uint4*)&Yout[obase + (size_t)i16 * 8] = *(const uint4*)&sO[i16 * 8];
    }
}

// ---------------------------------------------------------------------------
// K7: BN2 finalize folded into classifier weights:
//   wcs[c] = sc2[c]*Wc[c],  kc = sum_c sh2[c]*Wc[c] + bc
__global__ void k_bnfin2(const float* __restrict__ gsum, const float* __restrict__ gsq,
                         const float* __restrict__ gamma, const float* __restrict__ beta,
                         const float* __restrict__ Wc, const float* __restrict__ bc,
                         float* __restrict__ wcs, float* __restrict__ kc) {
    __shared__ float red[128];
    const int c = threadIdx.x;
    float s = 0.f, q = 0.f;
    for (int j = 0; j < NSLOTS; ++j) { s += gsum[j * 128 + c]; q += gsq[j * 128 + c]; }
    const float inv = 1.0f / (float)(Bb * Nn);
    const float mu  = s * inv;
    const float var = q * inv - mu * mu;
    const float sc  = gamma[c] * rsqrtf(var + BN_EPS);
    const float sh  = beta[c] - mu * sc;
    const float w   = Wc[c];
    wcs[c] = sc * w;
    red[c] = sh * w;
    __syncthreads();
    for (int st = 64; st; st >>= 1) {
        if (c < st) red[c] += red[c + st];
        __syncthreads();
    }
    if (c == 0) kc[0] = red[0] + bc[0];
}

// ---------------------------------------------------------------------------
// K8: classifier. Block = 16 nodes (4 waves x 4 nodes x 4 batches); reads stay
// wave-coalesced (1KB row per wave-read), results transit LDS, then 64 threads
// write four 64B contiguous chunks (was: 80000 scattered 4B stores).
__global__ __launch_bounds__(256) void k_cls(const unsigned* __restrict__ h2,
                                             const float* __restrict__ wcs,
                                             const float* __restrict__ kc,
                                             float* __restrict__ out) {
    __shared__ float sres[64];            // [b][node_local] = [4][16]
    const int w = threadIdx.x >> 6;
    const int lane = threadIdx.x & 63;
    const int n0 = blockIdx.x * 16;
    const float2 wc = *(const float2*)&wcs[lane * 2];
#pragma unroll
    for (int jj = 0; jj < 4; ++jj) {      // node n0 + w*4 + jj, batches 0..3
        const int node = n0 + w * 4 + jj;
#pragma unroll
        for (int b = 0; b < 4; ++b) {
            const size_t row = (size_t)node * 4 + b;
            const unsigned hv = h2[row * 64 + lane];
            float p = bf_lo(hv) * wc.x + bf_hi(hv) * wc.y;
#pragma unroll
            for (int off = 32; off; off >>= 1) p += __shfl_down(p, off);
            if (lane == 0) sres[b * 16 + w * 4 + jj] = p;
        }
    }
    __syncthreads();
    if (threadIdx.x < 64) {
        const int b = threadIdx.x >> 4, i = threadIdx.x & 15;
        out[(size_t)b * Nn + n0 + i] = sres[b * 16 + i] + kc[0];
    }
}

// ---------------------------------------------------------------------------
extern "C" void kernel_launch(void* const* d_in, const int* in_sizes, int n_in,
                              void* d_out, int out_size, void* d_ws, size_t ws_size,
                              hipStream_t stream) {
    const float* x      = (const float*)d_in[0];
    const int*   ei     = (const int*)d_in[1];
    const float* W1     = (const float*)d_in[2];
    const float* b1     = (const float*)d_in[3];
    const float* W2     = (const float*)d_in[4];
    const float* b2     = (const float*)d_in[5];
    const float* gamma1 = (const float*)d_in[6];
    const float* beta1  = (const float*)d_in[7];
    const float* gamma2 = (const float*)d_in[8];
    const float* beta2  = (const float*)d_in[9];
    const float* Wc     = (const float*)d_in[10];
    const float* bc     = (const float*)d_in[11];
    float* out = (float*)d_out;

    const int E = in_sizes[1] / 2;
    const int* src = ei;
    const int* dst = ei + E;

    char* ws = (char*)d_ws;
    size_t off = 0;
    auto alloc = [&](size_t bytes) -> char* {
        char* p = ws + off;
        off += (bytes + 255) & ~(size_t)255;
        return p;
    };
    // zero-init region: deg, nsum, gstat contiguous -> ONE memset
    int*      deg      = (int*)     alloc((size_t)Nn * 4);
    float*    nsum     = (float*)   alloc((size_t)Nn * 4);
    float*    gstat    = (float*)   alloc((size_t)4 * NSLOTS * 128 * 4);
    const size_t zspan = (size_t)((char*)(gstat + 4 * NSLOTS * 128) - (char*)deg);
    float* gsum1 = gstat;
    float* gsq1  = gstat + NSLOTS * 128;
    float* gsum2 = gstat + 2 * NSLOTS * 128;
    float* gsq2  = gstat + 3 * NSLOTS * 128;

    int*      cursor   = (int*)     alloc((size_t)Nn * 4);
    int*      rowptr   = (int*)     alloc((size_t)(Nn + 1) * 4);
    float*    dinv     = (float*)   alloc((size_t)Nn * 4);
    int*      csr_src  = (int*)     alloc((size_t)(E + Nn) * 4);
    float*    csr_norm = (float*)   alloc((size_t)(E + Nn) * 4);
    float*    wcs      = (float*)   alloc(128 * 4);
    float*    kc       = (float*)   alloc(256);
    unsigned short* WT1f = (unsigned short*)alloc((size_t)128 * Ff * 2);
    unsigned short* WT2f = (unsigned short*)alloc((size_t)128 * Hh * 2);
    float*          shW2 = (float*)         alloc((size_t)128 * 4);
    unsigned*       xb   = (unsigned*)      alloc((size_t)Nn * Bb * 32 * 4);  // bf16 x node-major
    unsigned short* h1b  = (unsigned short*)alloc((size_t)Bb * Nn * Hh * 2);  // bf16 [80000][128]
    unsigned short* h2b  = (unsigned short*)alloc((size_t)Bb * Nn * Hh * 2);  // bf16 [80000][128]

    (void)hipMemsetAsync(deg, 0, zspan, stream);

    // merged pre-pass: deg | cvt | wt1
    const int NDEG = (E + 255) / 256;
    const int NCVT = (Bb * Nn * 32) / 256;
    k_pre<<<NDEG + NCVT + 32, 256, 0, stream>>>(dst, E, NDEG, deg, x, xb, W1, WT1f);
    // one-launch redundant-prefix scan
    k_scanall<<<NB, 1024, 0, stream>>>(deg, rowptr, cursor, dinv);
    k_fill<<<(E + Nn + 255) / 256, 256, 0, stream>>>(src, dst, E, dinv, cursor,
                                                     csr_src, csr_norm, nsum);

    // Layer 1: fused agg(x)@W1 (+b1, ReLU, bf16 out); stats in separate pass
    k_fmm<Ff, false><<<Nn / 4, 128, 0, stream>>>(
        xb, rowptr, csr_src, csr_norm, WT1f, b1, nullptr, nullptr, h1b);
    k_stat<<<640, 256, 0, stream>>>((const unsigned*)h1b, gsum1, gsq1);
    // BN1 finalize + fold into WT2f/shW2
    k_prep2<<<65, 128, 0, stream>>>(gsum1, gsq1, gamma1, beta1, W2, WT2f, shW2);
    // Layer 2: fused agg(h1)@(sc1.W2) + nsum*(sh1@W2) + b2, ReLU, bf16 out
    k_fmm<Hh, true><<<Nn / 4, 128, 0, stream>>>(
        (const unsigned*)h1b, rowptr, csr_src, csr_norm, WT2f, b2, nsum, shW2, h2b);
    k_stat<<<640, 256, 0, stream>>>((const unsigned*)h2b, gsum2, gsq2);
    k_bnfin2<<<1, Hh, 0, stream>>>(gsum2, gsq2, gamma2, beta2, Wc, bc, wcs, kc);

    // Classifier (BN2 folded into wcs/kc)
    k_cls<<<Nn / 16, 256, 0, stream>>>((const unsigned*)h2b, wcs, kc, out);
}

// Round 18
// 178.678 us; speedup vs baseline: 1.2224x; 1.2224x over previous
//
#include <hip/hip_runtime.h>

// Problem constants (fixed by setup_inputs)
constexpr int Bb = 4;
constexpr int Nn = 20000;
constexpr int Ff = 64;
constexpr int Hh = 128;
constexpr float BN_EPS = 1e-5f;
constexpr int NSLOTS = 64;               // BN-stat atomic spread
constexpr int NB = (Nn + 1023) / 1024;   // scan blocks (20)

typedef __attribute__((ext_vector_type(8))) short bf16x8;
typedef __attribute__((ext_vector_type(4))) float f32x4;

// bf16 helpers (RNE pack, cheap unpack)
__device__ inline unsigned f2bf(float f) {
    unsigned u = __float_as_uint(f);
    return (u + 0x7fffu + ((u >> 16) & 1u)) >> 16;
}
__device__ inline unsigned pack2(float lo, float hi) { return f2bf(lo) | (f2bf(hi) << 16); }
__device__ inline float bf_lo(unsigned w) { return __uint_as_float(w << 16); }
__device__ inline float bf_hi(unsigned w) { return __uint_as_float(w & 0xffff0000u); }

template <int NU>
__device__ inline void ldrow(unsigned* u, const unsigned* p) {
    if constexpr (NU == 2) { const uint2 t = *(const uint2*)p; u[0] = t.x; u[1] = t.y; }
    else { const uint4 t = *(const uint4*)p; u[0] = t.x; u[1] = t.y; u[2] = t.z; u[3] = t.w; }
}
template <int NU>
__device__ inline void acc_row(float* a, const unsigned* u, float nm) {
#pragma unroll
    for (int c = 0; c < NU; ++c) {
        a[2 * c]     = fmaf(nm, bf_lo(u[c]), a[2 * c]);
        a[2 * c + 1] = fmaf(nm, bf_hi(u[c]), a[2 * c + 1]);
    }
}

// ---------------------------------------------------------------------------
// K1: merged pre-pass: [0,NDEG) deg-count | [NDEG,NDEG+NCVT) x->bf16 cvt
// (output-linear: contiguous xb writes) | [+32) W1 frag-linear transpose.
__global__ __launch_bounds__(256) void k_pre(const int* __restrict__ dst, int E,
                                             int NDEG,
                                             int* __restrict__ deg,
                                             const float* __restrict__ x,
                                             unsigned* __restrict__ xb,
                                             const float* __restrict__ W1,
                                             unsigned short* __restrict__ WTf) {
    const int b = blockIdx.x;
    if (b < NDEG) {
        const int e = b * 256 + threadIdx.x;
        if (e < E) atomicAdd(&deg[dst[e]], 1);
    } else if (b < NDEG + (Bb * Nn * 32) / 256) {
        const int o = (b - NDEG) * 256 + threadIdx.x;   // OUTPUT uint index
        const int n   = o >> 7;           // node
        const int rem = o & 127;
        const int bb  = rem >> 5;         // batch
        const int c2  = rem & 31;         // channel pair
        const float2 v = *(const float2*)&x[(((size_t)bb * Nn + n) * 64) + c2 * 2];
        xb[o] = pack2(v.x, v.y);
    } else {
        const int f = (b - NDEG - (Bb * Nn * 32) / 256) * 256 + threadIdx.x;
        if (f < 128 * Ff) {
            const int j = f & 7, lane = (f >> 3) & 63, rest = f >> 9;
            const int ks = rest & 1, tt = rest >> 1;
            const int col = tt * 16 + (lane & 15);
            const int k = ks * 32 + ((lane >> 4) << 3) + j;
            WTf[f] = (unsigned short)f2bf(W1[(size_t)k * 128 + col]);
        }
    }
}

// ---------------------------------------------------------------------------
// K2: ONE-launch scan. Each of NB blocks redundantly sums its prefix of
// (deg+1), then scans its own tile locally. No inter-block handoff.
__global__ __launch_bounds__(1024) void k_scanall(const int* __restrict__ deg,
                                                  int* __restrict__ rowptr,
                                                  int* __restrict__ cursor,
                                                  float* __restrict__ dinv) {
    __shared__ int red[16];
    __shared__ int woff[16];
    __shared__ int base_s;
    const int tid = threadIdx.x, lane = tid & 63, wid = tid >> 6;
    const int b = blockIdx.x;

    int pre = 0;
    for (int i = tid; i < b * 1024; i += 1024) pre += deg[i] + 1;
#pragma unroll
    for (int d = 32; d; d >>= 1) pre += __shfl_down(pre, d);
    if (lane == 0) red[wid] = pre;
    __syncthreads();                      // B1
    if (tid == 0) {
        int s = 0;
        for (int w = 0; w < 16; ++w) s += red[w];
        base_s = s;
    }

    const int i = b * 1024 + tid;
    const int cnt = (i < Nn) ? deg[i] + 1 : 0;
    int v = cnt;
#pragma unroll
    for (int d = 1; d < 64; d <<= 1) {
        const int t = __shfl_up(v, d);
        if (lane >= d) v += t;
    }
    __syncthreads();                      // B2
    if (lane == 63) red[wid] = v;
    __syncthreads();                      // B3
    if (wid == 0) {
        const int orig = (lane < 16) ? red[lane] : 0;
        int w = orig;
#pragma unroll
        for (int d = 1; d < 16; d <<= 1) {
            const int t = __shfl_up(w, d);
            if (lane >= d) w += t;
        }
        if (lane < 16) woff[lane] = w - orig;
    }
    __syncthreads();                      // B4
    if (i < Nn) {
        const int excl = base_s + woff[wid] + (v - cnt);
        rowptr[i] = excl;
        cursor[i] = excl;
        dinv[i] = rsqrtf((float)cnt);
        if (i == Nn - 1) rowptr[Nn] = excl + cnt;
    }
}

// ---------------------------------------------------------------------------
// K3: fill CSR + per-edge norm + per-node nsum (= sum of norms, for BN-fold)
__global__ void k_fill(const int* __restrict__ src, const int* __restrict__ dst, int E,
                       const float* __restrict__ dinv, int* __restrict__ cursor,
                       int* __restrict__ csr_src, float* __restrict__ csr_norm,
                       float* __restrict__ nsum) {
    int t = blockIdx.x * blockDim.x + threadIdx.x;
    int s, d;
    if (t < E) { s = src[t]; d = dst[t]; }
    else if (t < E + Nn) { s = d = t - E; }
    else return;
    int pos = atomicAdd(&cursor[d], 1);
    const float nm = dinv[s] * dinv[d];
    csr_src[pos]  = s;
    csr_norm[pos] = nm;
    atomicAdd(&nsum[d], nm);
}

// ---------------------------------------------------------------------------
// K4: fused BN1-finalize + WT2 fold (frag-linear) + shW2. Every block
// redundantly reduces 64-slot stats; blocks 0..63 write WT2f, block 64 shW2.
__global__ __launch_bounds__(128) void k_prep2(const float* __restrict__ gsum,
                                               const float* __restrict__ gsq,
                                               const float* __restrict__ gamma,
                                               const float* __restrict__ beta,
                                               const float* __restrict__ W2,
                                               unsigned short* __restrict__ WT2f,
                                               float* __restrict__ shW2) {
    __shared__ float sc_s[128], sh_s[128];
    const int c = threadIdx.x;
    float s = 0.f, q = 0.f;
    for (int j = 0; j < NSLOTS; ++j) { s += gsum[j * 128 + c]; q += gsq[j * 128 + c]; }
    const float inv = 1.0f / (float)(Bb * Nn);
    const float mu  = s * inv;
    const float var = q * inv - mu * mu;
    const float sc  = gamma[c] * rsqrtf(var + BN_EPS);
    sc_s[c] = sc;
    sh_s[c] = beta[c] - mu * sc;
    __syncthreads();
    if (blockIdx.x < 64) {
#pragma unroll
        for (int i = 0; i < 2; ++i) {
            const int f = blockIdx.x * 256 + i * 128 + c;
            const int j = f & 7, lane = (f >> 3) & 63, rest = f >> 9;  // 0..31
            const int ks = rest & 3, tt = rest >> 2;
            const int col = tt * 16 + (lane & 15);
            const int k = ks * 32 + ((lane >> 4) << 3) + j;
            WT2f[f] = (unsigned short)f2bf(sc_s[k] * W2[(size_t)k * 128 + col]);
        }
    } else {
        float a = 0.f;
        for (int k = 0; k < 128; ++k) a = fmaf(sh_s[k], W2[(size_t)k * 128 + c], a);
        shW2[c] = a;
    }
}

// ---------------------------------------------------------------------------
// K5: FUSED gather-aggregate + MFMA GEMM — R10's verified 184us config:
// one-wave block = 4 nodes = 16 rows, grid Nn/4 = 5000, unroll 8, private sA,
// zero barriers, B-frags direct from frag-linear WTf, in-kernel BN stats via
// shfl_xor + 64-slot spread (78-way: benign per R10 counters).
template <int K, bool L2E>
__global__ __launch_bounds__(64, 6) void k_fmm(const unsigned* __restrict__ G,
                                               const int* __restrict__ rowptr,
                                               const int* __restrict__ csr_src,
                                               const float* __restrict__ csr_norm,
                                               const unsigned short* __restrict__ WTf,
                                               const float* __restrict__ bias,
                                               const float* __restrict__ nsum,
                                               const float* __restrict__ shW2,
                                               unsigned short* __restrict__ Yout,
                                               float* __restrict__ gsum,
                                               float* __restrict__ gsq) {
    constexpr int NKS = K / 32;
    constexpr int AST = K + 8;
    constexpr int NU = K / 32;        // uints per lane per edge (2 or 4)
    constexpr int ROWU = Bb * K / 2;  // uints per node row (128 or 256)
    __shared__ alignas(16) unsigned short sA[16 * AST];

    const int lane = threadIdx.x;
    const int cg = lane & 15, kg = lane >> 4;
    const int g = blockIdx.x;         // node group: nodes 4g..4g+3
    const int row0 = g * 16;

    // gather 4 nodes into private sA (no cross-wave deps, no barriers)
#pragma unroll
    for (int j = 0; j < 4; ++j) {
        const int v = g * 4 + j;
        const int beg = rowptr[v], end = rowptr[v + 1];
        float a[2 * NU];
#pragma unroll
        for (int c = 0; c < 2 * NU; ++c) a[c] = 0.f;
        int e = beg;
        for (; e + 8 <= end; e += 8) {     // 8 outstanding 1KB gathers
            unsigned u[8][NU];
            int si[8];
#pragma unroll
            for (int q = 0; q < 8; ++q) si[q] = csr_src[e + q];
#pragma unroll
            for (int q = 0; q < 8; ++q)
                ldrow<NU>(u[q], G + (size_t)si[q] * ROWU + lane * NU);
#pragma unroll
            for (int q = 0; q < 8; ++q) acc_row<NU>(a, u[q], csr_norm[e + q]);
        }
        for (; e + 4 <= end; e += 4) {
            unsigned u[4][NU];
            int si[4];
#pragma unroll
            for (int q = 0; q < 4; ++q) si[q] = csr_src[e + q];
#pragma unroll
            for (int q = 0; q < 4; ++q)
                ldrow<NU>(u[q], G + (size_t)si[q] * ROWU + lane * NU);
#pragma unroll
            for (int q = 0; q < 4; ++q) acc_row<NU>(a, u[q], csr_norm[e + q]);
        }
        for (; e < end; ++e) {
            unsigned u[NU];
            ldrow<NU>(u, G + (size_t)csr_src[e] * ROWU + lane * NU);
            acc_row<NU>(a, u, csr_norm[e]);
        }
        const int row = j * 4 + kg;       // node-major row = node*4 + batch
        unsigned p[NU];
#pragma unroll
        for (int c = 0; c < NU; ++c) p[c] = pack2(a[2 * c], a[2 * c + 1]);
        if constexpr (NU == 2) *(uint2*)&sA[row * AST + cg * 4] = *(const uint2*)p;
        else                   *(uint4*)&sA[row * AST + cg * 8] = *(const uint4*)p;
    }
    // same-wave LDS RAW: compiler lgkmcnt handles ordering; no barrier.

    // MFMA: rows 0..15 (rowL = cg), 128 cols; B direct from global WTf
    f32x4 acc[8];
#pragma unroll
    for (int t = 0; t < 8; ++t) acc[t] = (f32x4){0.f, 0.f, 0.f, 0.f};
#pragma unroll
    for (int ks = 0; ks < NKS; ++ks) {
        const bf16x8 av = *(const bf16x8*)&sA[cg * AST + ks * 32 + kg * 8];
#pragma unroll
        for (int t = 0; t < 8; ++t) {
            const bf16x8 bv = *(const bf16x8*)&WTf[(size_t)((t * NKS + ks) * 64 + lane) * 8];
            acc[t] = __builtin_amdgcn_mfma_f32_16x16x32_bf16(av, bv, acc[t], 0, 0, 0);
        }
    }

    // epilogue: +bias (+ns*shW2 for L2E), ReLU, bf16 store; BN stats via
    // shfl_xor over kg (node axis) then 16 lanes atomicAdd per col-tile.
    const int rbase = kg * 4;             // 4 regs = 4 batches of node (g*4+kg)
    float ns = 0.f;
    if (L2E) ns = nsum[g * 4 + kg];
    float* gs = gsum + (size_t)(g & (NSLOTS - 1)) * 128;
    float* gq = gsq  + (size_t)(g & (NSLOTS - 1)) * 128;
#pragma unroll
    for (int t = 0; t < 8; ++t) {
        const int col = t * 16 + cg;
        float badd = bias[col];
        if (L2E) badd = fmaf(ns, shW2[col], badd);
        float s = 0.f, q = 0.f;
#pragma unroll
        for (int jj = 0; jj < 4; ++jj) {
            const float y = fmaxf(acc[t][jj] + badd, 0.f);
            Yout[(size_t)(row0 + rbase + jj) * 128 + col] = (unsigned short)f2bf(y);
            s += y; q = fmaf(y, y, q);
        }
        s += __shfl_xor(s, 16); s += __shfl_xor(s, 32);   // sum over kg
        q += __shfl_xor(q, 16); q += __shfl_xor(q, 32);
        if (kg == 0) { atomicAdd(&gs[col], s); atomicAdd(&gq[col], q); }
    }
}

// ---------------------------------------------------------------------------
// K6: BN2 finalize folded into classifier weights:
//   wcs[c] = sc2[c]*Wc[c],  kc = sum_c sh2[c]*Wc[c] + bc
__global__ void k_bnfin2(const float* __restrict__ gsum, const float* __restrict__ gsq,
                         const float* __restrict__ gamma, const float* __restrict__ beta,
                         const float* __restrict__ Wc, const float* __restrict__ bc,
                         float* __restrict__ wcs, float* __restrict__ kc) {
    __shared__ float red[128];
    const int c = threadIdx.x;
    float s = 0.f, q = 0.f;
    for (int j = 0; j < NSLOTS; ++j) { s += gsum[j * 128 + c]; q += gsq[j * 128 + c]; }
    const float inv = 1.0f / (float)(Bb * Nn);
    const float mu  = s * inv;
    const float var = q * inv - mu * mu;
    const float sc  = gamma[c] * rsqrtf(var + BN_EPS);
    const float sh  = beta[c] - mu * sc;
    const float w   = Wc[c];
    wcs[c] = sc * w;
    red[c] = sh * w;
    __syncthreads();
    for (int st = 64; st; st >>= 1) {
        if (c < st) red[c] += red[c + st];
        __syncthreads();
    }
    if (c == 0) kc[0] = red[0] + bc[0];
}

// ---------------------------------------------------------------------------
// K7: classifier. Block = 16 nodes (4 waves x 4 nodes x 4 batches); reads
// wave-coalesced, results transit LDS, 64 threads write four 64B chunks.
__global__ __launch_bounds__(256) void k_cls(const unsigned* __restrict__ h2,
                                             const float* __restrict__ wcs,
                                             const float* __restrict__ kc,
                                             float* __restrict__ out) {
    __shared__ float sres[64];            // [b][node_local] = [4][16]
    const int w = threadIdx.x >> 6;
    const int lane = threadIdx.x & 63;
    const int n0 = blockIdx.x * 16;
    const float2 wc = *(const float2*)&wcs[lane * 2];
#pragma unroll
    for (int jj = 0; jj < 4; ++jj) {
        const int node = n0 + w * 4 + jj;
#pragma unroll
        for (int b = 0; b < 4; ++b) {
            const size_t row = (size_t)node * 4 + b;
            const unsigned hv = h2[row * 64 + lane];
            float p = bf_lo(hv) * wc.x + bf_hi(hv) * wc.y;
#pragma unroll
            for (int off = 32; off; off >>= 1) p += __shfl_down(p, off);
            if (lane == 0) sres[b * 16 + w * 4 + jj] = p;
        }
    }
    __syncthreads();
    if (threadIdx.x < 64) {
        const int b = threadIdx.x >> 4, i = threadIdx.x & 15;
        out[(size_t)b * Nn + n0 + i] = sres[b * 16 + i] + kc[0];
    }
}

// ---------------------------------------------------------------------------
extern "C" void kernel_launch(void* const* d_in, const int* in_sizes, int n_in,
                              void* d_out, int out_size, void* d_ws, size_t ws_size,
                              hipStream_t stream) {
    const float* x      = (const float*)d_in[0];
    const int*   ei     = (const int*)d_in[1];
    const float* W1     = (const float*)d_in[2];
    const float* b1     = (const float*)d_in[3];
    const float* W2     = (const float*)d_in[4];
    const float* b2     = (const float*)d_in[5];
    const float* gamma1 = (const float*)d_in[6];
    const float* beta1  = (const float*)d_in[7];
    const float* gamma2 = (const float*)d_in[8];
    const float* beta2  = (const float*)d_in[9];
    const float* Wc     = (const float*)d_in[10];
    const float* bc     = (const float*)d_in[11];
    float* out = (float*)d_out;

    const int E = in_sizes[1] / 2;
    const int* src = ei;
    const int* dst = ei + E;

    char* ws = (char*)d_ws;
    size_t off = 0;
    auto alloc = [&](size_t bytes) -> char* {
        char* p = ws + off;
        off += (bytes + 255) & ~(size_t)255;
        return p;
    };
    // zero-init region: deg, nsum, gstat contiguous -> ONE memset
    int*      deg      = (int*)     alloc((size_t)Nn * 4);
    float*    nsum     = (float*)   alloc((size_t)Nn * 4);
    float*    gstat    = (float*)   alloc((size_t)4 * NSLOTS * 128 * 4);
    const size_t zspan = (size_t)((char*)(gstat + 4 * NSLOTS * 128) - (char*)deg);
    float* gsum1 = gstat;
    float* gsq1  = gstat + NSLOTS * 128;
    float* gsum2 = gstat + 2 * NSLOTS * 128;
    float* gsq2  = gstat + 3 * NSLOTS * 128;

    int*      cursor   = (int*)     alloc((size_t)Nn * 4);
    int*      rowptr   = (int*)     alloc((size_t)(Nn + 1) * 4);
    float*    dinv     = (float*)   alloc((size_t)Nn * 4);
    int*      csr_src  = (int*)     alloc((size_t)(E + Nn) * 4);
    float*    csr_norm = (float*)   alloc((size_t)(E + Nn) * 4);
    float*    wcs      = (float*)   alloc(128 * 4);
    float*    kc       = (float*)   alloc(256);
    unsigned short* WT1f = (unsigned short*)alloc((size_t)128 * Ff * 2);
    unsigned short* WT2f = (unsigned short*)alloc((size_t)128 * Hh * 2);
    float*          shW2 = (float*)         alloc((size_t)128 * 4);
    unsigned*       xb   = (unsigned*)      alloc((size_t)Nn * Bb * 32 * 4);  // bf16 x node-major
    unsigned short* h1b  = (unsigned short*)alloc((size_t)Bb * Nn * Hh * 2);  // bf16 [80000][128]
    unsigned short* h2b  = (unsigned short*)alloc((size_t)Bb * Nn * Hh * 2);  // bf16 [80000][128]

    (void)hipMemsetAsync(deg, 0, zspan, stream);

    // merged pre-pass: deg | cvt | wt1
    const int NDEG = (E + 255) / 256;
    const int NCVT = (Bb * Nn * 32) / 256;
    k_pre<<<NDEG + NCVT + 32, 256, 0, stream>>>(dst, E, NDEG, deg, x, xb, W1, WT1f);
    // one-launch redundant-prefix scan
    k_scanall<<<NB, 1024, 0, stream>>>(deg, rowptr, cursor, dinv);
    k_fill<<<(E + Nn + 255) / 256, 256, 0, stream>>>(src, dst, E, dinv, cursor,
                                                     csr_src, csr_norm, nsum);

    // Layer 1: fused agg(x)@W1 (+b1, ReLU, BN1 stats in-kernel, bf16 out)
    k_fmm<Ff, false><<<Nn / 4, 64, 0, stream>>>(
        xb, rowptr, csr_src, csr_norm, WT1f, b1, nullptr, nullptr, h1b, gsum1, gsq1);
    // BN1 finalize + fold into WT2f/shW2
    k_prep2<<<65, 128, 0, stream>>>(gsum1, gsq1, gamma1, beta1, W2, WT2f, shW2);
    // Layer 2: fused agg(h1)@(sc1.W2) + nsum*(sh1@W2) + b2, ReLU, BN2 stats
    k_fmm<Hh, true><<<Nn / 4, 64, 0, stream>>>(
        (const unsigned*)h1b, rowptr, csr_src, csr_norm, WT2f, b2, nsum, shW2,
        h2b, gsum2, gsq2);
    k_bnfin2<<<1, Hh, 0, stream>>>(gsum2, gsq2, gamma2, beta2, Wc, bc, wcs, kc);

    // Classifier (BN2 folded into wcs/kc)
    k_cls<<<Nn / 16, 256, 0, stream>>>((const unsigned*)h2b, wcs, kc, out);
}